// Round 8
// baseline (264.145 us; speedup 1.0000x reference)
//
#include <hip/hip_runtime.h>
#include <hip/hip_cooperative_groups.h>

namespace cg = cooperative_groups;

#define G 64
#define TT 4096
#define EDGES 131072
#define NBLK 512
#define NTHR 256

#define OUT_ETOT 0
#define OUT_NODEE 64
#define OUT_Q (64 + 4096)
#define OUT_NF (64 + 4096 + 4096)

typedef unsigned long long ull;

struct Params {
    const int* ei;
    const float* elen;
    const float* node_attrs;
    const float* kappa;
    const float* ref_eta;
    const float* ref_log_sigma;
    const float* ref_A;
    const float* ref_B;
    const float* ref_C;
    const float* ref_D;
    const float* ref_mu;
    const float* short_e;
    const float* atomic_short;
    const float* nf_in;
    ull* packed;
    float* factor_g;
    float* fcf_g;
    float* aE2b;
    float* qc;
    float* qsum;
    float* out;
};

__device__ __forceinline__ float wave_sum_f(float v) {
#pragma unroll
    for (int m = 1; m < 64; m <<= 1) v += __shfl_xor(v, m);
    return v;
}
__device__ __forceinline__ double wave_sum_d(double v) {
#pragma unroll
    for (int m = 1; m < 64; m <<= 1) v += __shfl_xor(v, m);
    return v;
}
__device__ __forceinline__ double bcast_d(double v, int j) {
    union { double d; int i[2]; } u;
    u.d = v;
    union { int i[2]; double d; } r;
    r.i[0] = __builtin_amdgcn_readlane(u.i[0], j);
    r.i[1] = __builtin_amdgcn_readlane(u.i[1], j);
    return r.d;
}
__device__ __forceinline__ int type_of(float4 na) {
    int t = 0;
    float best = na.x;
    if (na.y > best) { best = na.y; t = 1; }
    if (na.z > best) { best = na.z; t = 2; }
    if (na.w > best) { best = na.w; t = 3; }
    return t;
}
__device__ __forceinline__ float fcut(float R, float c1) {
    if (R < 1.0f) return c1;             // R is always > 0 here
    if (R > 6.0f) return 0.0f;
    float x = 1.0f - (R - 1.0f) * 0.2f;  // in [0,1]
    float ex = __expf(2.0f * x);
    float t = (ex - 1.0f) / (ex + 1.0f); // tanh(x)
    return t * t * t;
}

__global__ __launch_bounds__(NTHR, 2) void k_all(Params p) {
    cg::grid_group grid = cg::this_grid();
    const int tid = threadIdx.x;
    const int bid = blockIdx.x;
    const int gtid = bid * NTHR + tid;     // 0..131071
    const int lane = tid & 63;
    const int wv = tid >> 6;
    const int W = (bid << 2) + wv;         // wave id 0..2047 (2 rows each)
    const float SQRT_PI = 1.7724538509055159f;
    const float th1 = tanhf(1.0f);
    const float c1 = th1 * th1 * th1;

    __shared__ float sL[64][65];
    __shared__ float s_diag[64];
    __shared__ float s_red[4];

    // ---- phase 0: zero packed (2 MiB) + init E_tot with short_energy --------
    ((ulonglong2*)p.packed)[gtid] = make_ulonglong2(0ull, 0ull);
    if (bid == 0 && tid < G) p.out[OUT_ETOT + tid] = p.short_e[tid];
    grid.sync();

    // ---- phase 1: edge scatter, packed (edge_idx<<32 | R bits) --------------
    {
        int e = gtid;                              // exactly EDGES threads
        int i = p.ei[e];
        int j = p.ei[EDGES + e];
        float R = p.elen[e];                       // in [1,6] -> bits > 0
        ull v = ((ull)(unsigned)e << 32) | (ull)__float_as_uint(R);
        atomicMax(&p.packed[(i << 6) + (j & 63)], v);
    }
    grid.sync();

    // ---- phase 2: build factor/fcf + E2b row sums + feats copy --------------
    {
        // feats copy (independent of everything): 2 float2 per thread
#pragma unroll
        for (int k = 0; k < 2; ++k) {
            int idx = gtid + k * (NBLK * NTHR);    // 0..262143
            int i = idx >> 6, c = idx & 63;
            float2 v = ((const float2*)p.nf_in)[idx];
            *(float2*)(p.out + OUT_NF + (size_t)i * 130 + c * 2) = v;
        }
        const int g = W >> 5;                      // graph of rows 2W,2W+1
        const float4 na =
            *(const float4*)(p.node_attrs + ((size_t)((g << 6) + lane) << 2));
        const int tj = type_of(na);
        const float sgj = __expf(p.ref_log_sigma[tj]);
        float e2[2];
#pragma unroll
        for (int r = 0; r < 2; ++r) {
            const int row = (W << 1) + r;
            const int ir = row & 63;
            const ull pk = p.packed[((size_t)row << 6) + lane];
            const int ti = __shfl(tj, ir);
            const float sgi = __shfl(sgj, ir);
            const float gam = sqrtf(sgi * sgi + sgj * sgj);
            const float R = (pk > 0ull) ? __uint_as_float((unsigned)pk) : 0.5f;
            const float rinv = __frcp_rn(R);
            const float factor = erff(R * (0.70710678118654752f / gam)) * rinv;
            const float fc = fcut(R, c1);
            p.factor_g[((size_t)row << 6) + lane] = factor;
            p.fcf_g[((size_t)row << 6) + lane] = factor * fc;
            float e = 0.0f;
            if (ir != lane) {
                int t4 = ti * 4 + tj;
                float r2 = rinv * rinv;
                float r6 = r2 * r2 * r2;
                e = (p.ref_A[t4] * __expf(p.ref_B[t4] * (p.ref_mu[t4] - R)) -
                     p.ref_C[t4] * r6 - p.ref_D[t4] * (r6 * r2)) * fc;
            }
            e2[r] = e;
        }
#pragma unroll
        for (int m = 1; m < 64; m <<= 1) {
            e2[0] += __shfl_xor(e2[0], m);
            e2[1] += __shfl_xor(e2[1], m);
        }
        if (lane == 0) {
            p.aE2b[(W << 1)] = 0.5f * e2[0];
            p.aE2b[(W << 1) + 1] = 0.5f * e2[1];
        }
    }
    grid.sync();

    // ---- phase 3: per-graph fp64 dual forward substitution (blocks 0..63) ---
    if (bid < G) {
        const int g = bid;
        const float4* src4 = (const float4*)(p.factor_g + ((size_t)g << 12));
#pragma unroll
        for (int k = 0; k < 4; ++k) {
            int f = k * NTHR + tid;                // float4 index 0..1023
            float4 v = src4[f];
            int rr = f >> 4, cc = (f & 15) << 2;
            sL[rr][cc] = v.x; sL[rr][cc + 1] = v.y;
            sL[rr][cc + 2] = v.z; sL[rr][cc + 3] = v.w;
        }
        if (tid < 64) {
            float4 na =
                *(const float4*)(p.node_attrs + ((size_t)((g << 6) + tid) << 2));
            int t = type_of(na);
            float sg = __expf(p.ref_log_sigma[t]);
            s_diag[tid] = p.ref_eta[t] + 1.0f / (sg * SQRT_PI);
        }
        __syncthreads();
        if (tid < 64) {
            const int i = tid;
            double Ld = (double)(s_diag[i] + sL[i][i]);
            double inv = 1.0 / Ld;
            double au = 1.0;
            double av = (double)p.kappa[(g << 6) + i];
            double my_u = 0.0, my_v = 0.0;
            for (int j = 0; j < 64; ++j) {
                double ij = bcast_d(inv, j);
                double uj = bcast_d(au, j) * ij;
                double vj = bcast_d(av, j) * ij;
                if (i == j) { my_u = uj; my_v = vj; }
                if (i > j) {
                    double Lij = (double)sL[i][j];
                    au -= Lij * uj;
                    av -= Lij * vj;
                }
            }
            double Su = wave_sum_d(my_u);
            double Sv = wave_sum_d(my_v);
            double lam = Sv / Su;  // q = -v + (Sv/Su)u  => sum(q)=0
            float q = (float)(-my_v + lam * my_u);
            p.qc[(g << 6) + i] = q;
            float sq = wave_sum_f(q);
            if (i == 0) p.qsum[g] = sq;
        }
    }
    grid.sync();

    // ---- phase 4: matvec row sums + epilogue --------------------------------
    {
        const int g = W >> 5;
        const float qj = p.qc[(g << 6) + lane];
        const float qs = p.qsum[lane];
        const float4 na =
            *(const float4*)(p.node_attrs + ((size_t)((g << 6) + lane) << 2));
        const int tj = type_of(na);
        const float sgj = __expf(p.ref_log_sigma[tj]);
        const float factor_off = erff(0.70710678118654752f / 0.5f) * 2.0f;

        float pr[2], wr[2];
#pragma unroll
        for (int r = 0; r < 2; ++r) {
            const int row = (W << 1) + r;
            const float f = p.factor_g[((size_t)row << 6) + lane];
            const float fcf = p.fcf_g[((size_t)row << 6) + lane];
            pr[r] = fcf * qj;
            wr[r] = f * qj;
        }
#pragma unroll
        for (int m = 1; m < 64; m <<= 1) {  // 4 interleaved butterflies
            pr[0] += __shfl_xor(pr[0], m);
            pr[1] += __shfl_xor(pr[1], m);
            wr[0] += __shfl_xor(wr[0], m);
            wr[1] += __shfl_xor(wr[1], m);
        }
        const float Qall = wave_sum_f(qs);
        const float qsg = __shfl(qs, g);   // qsum[g]
        float acc = 0.0f;
#pragma unroll
        for (int r = 0; r < 2; ++r) {
            const int row = (W << 1) + r;
            const int ir = row & 63;
            const float q = __shfl(qj, ir);    // qc[row]
            const float sgi = __shfl(sgj, ir); // own-row sigma
            if (lane == 0) {
                float off = Qall - qsg;
                float e2 = p.aE2b[row];
                float coef = 0.5f / (sgi * SQRT_PI);
                float ap = pr[r] + factor_off * c1 * off;
                float V = wr[r] + factor_off * off + coef * q;
                float aEel = q * V;
                p.out[OUT_NODEE + row] = aEel + e2 + p.atomic_short[row];
                p.out[OUT_Q + row] = q;
                p.out[OUT_NF + (size_t)row * 130 + 128] = q;
                p.out[OUT_NF + (size_t)row * 130 + 129] = ap;
                acc += aEel + e2;
            }
        }
        if (lane == 0) s_red[wv] = acc;
        __syncthreads();
        if (tid == 0) {
            // one atomic per block (8 rows, all in graph g)
            atomicAdd(&p.out[OUT_ETOT + g],
                      s_red[0] + s_red[1] + s_red[2] + s_red[3]);
        }
    }
}

extern "C" void kernel_launch(void* const* d_in, const int* in_sizes, int n_in,
                              void* d_out, int out_size, void* d_ws, size_t ws_size,
                              hipStream_t stream) {
    char* ws = (char*)d_ws;
    Params prm;
    prm.ei = (const int*)d_in[2];
    prm.elen = (const float*)d_in[3];
    prm.node_attrs = (const float*)d_in[1];
    prm.kappa = (const float*)d_in[4];
    prm.ref_eta = (const float*)d_in[6];
    prm.ref_log_sigma = (const float*)d_in[7];
    prm.ref_A = (const float*)d_in[8];
    prm.ref_B = (const float*)d_in[9];
    prm.ref_C = (const float*)d_in[10];
    prm.ref_D = (const float*)d_in[11];
    prm.ref_mu = (const float*)d_in[12];
    prm.short_e = (const float*)d_in[13];
    prm.atomic_short = (const float*)d_in[14];
    prm.nf_in = (const float*)d_in[5];
    prm.packed = (ull*)ws;                                  // 2 MiB
    prm.factor_g = (float*)(ws + (2u << 20));               // 1 MiB
    prm.fcf_g = prm.factor_g + (size_t)TT * 64;             // 1 MiB
    prm.aE2b = prm.fcf_g + (size_t)TT * 64;                 // 16 KiB
    prm.qc = prm.aE2b + TT;                                 // 16 KiB
    prm.qsum = prm.qc + TT;                                 // 256 B
    prm.out = (float*)d_out;

    void* args[] = { (void*)&prm };
    hipLaunchCooperativeKernel((const void*)k_all, dim3(NBLK), dim3(NTHR),
                               args, 0, stream);
}

// Round 9
// 31.690 us; speedup vs baseline: 8.3352x; 8.3352x over previous
//
#include <hip/hip_runtime.h>

#define G 64
#define TT 4096
#define EDGES 131072

#define OUT_ETOT 0
#define OUT_NODEE 64
#define OUT_Q (64 + 4096)
#define OUT_NF (64 + 4096 + 4096)

typedef unsigned long long ull;

__device__ __forceinline__ float wave_sum_f(float v) {
#pragma unroll
    for (int m = 1; m < 64; m <<= 1) v += __shfl_xor(v, m);
    return v;
}
__device__ __forceinline__ double wave_sum_d(double v) {
#pragma unroll
    for (int m = 1; m < 64; m <<= 1) v += __shfl_xor(v, m);
    return v;
}
__device__ __forceinline__ double bcast_d(double v, int j) {
    union { double d; int i[2]; } u;
    u.d = v;
    union { int i[2]; double d; } r;
    r.i[0] = __builtin_amdgcn_readlane(u.i[0], j);
    r.i[1] = __builtin_amdgcn_readlane(u.i[1], j);
    return r.d;
}
__device__ __forceinline__ int type_of(float4 na) {
    int t = 0;
    float best = na.x;
    if (na.y > best) { best = na.y; t = 1; }
    if (na.z > best) { best = na.z; t = 2; }
    if (na.w > best) { best = na.w; t = 3; }
    return t;
}
__device__ __forceinline__ float fcut(float R, float c1) {
    if (R < 1.0f) return c1;             // R is always > 0 here
    if (R > 6.0f) return 0.0f;
    float x = 1.0f - (R - 1.0f) * 0.2f;  // in [0,1]
    float ex = __expf(2.0f * x);
    float t = (ex - 1.0f) / (ex + 1.0f); // tanh(x)
    return t * t * t;
}

// ---- k_prep: zero packed (2 MiB) + feats copy (2 MiB, stride-130 rows) -------
__global__ __launch_bounds__(256) void k_prep(ulonglong2* __restrict__ packed,
                                              const float* __restrict__ nf_in,
                                              float* __restrict__ out) {
    const int idx = blockIdx.x * 256 + threadIdx.x;  // 0..131071
    packed[idx] = make_ulonglong2(0ull, 0ull);
#pragma unroll
    for (int k = 0; k < 2; ++k) {
        int t = idx + k * 131072;                    // 0..262143 float2 units
        int i = t >> 6, c = t & 63;
        float2 v = ((const float2*)nf_in)[t];
        *(float2*)(out + OUT_NF + (size_t)i * 130 + c * 2) = v;
    }
}

// ---- k_scatter: pack (edge_idx | R_bits); max == last-write-wins by order ----
__global__ __launch_bounds__(256) void k_scatter(const int* __restrict__ ei,
                                                 const float* __restrict__ elen,
                                                 ull* __restrict__ packed) {
    int e = blockIdx.x * blockDim.x + threadIdx.x;
    if (e >= EDGES) return;
    int i = ei[e];
    int j = ei[EDGES + e];
    float R = elen[e];                        // in [1,6] -> bits > 0
    ull v = ((ull)(unsigned)e << 32) | (ull)__float_as_uint(R);
    atomicMax(&packed[(i << 6) + (j & 63)], v);
}

// ---- k_main: one block per graph; build + solve + epilogue, LDS-resident -----
// sum(q)=0 per graph exactly (constraint row), so the cross-graph "off" term
// is O(solver eps) and dropped -> graphs are fully independent.
__global__ __launch_bounds__(1024, 1) void k_main(
    const ull* __restrict__ packed, const float* __restrict__ node_attrs,
    const float* __restrict__ kappa, const float* __restrict__ ref_eta,
    const float* __restrict__ ref_log_sigma, const float* __restrict__ ref_A,
    const float* __restrict__ ref_B, const float* __restrict__ ref_C,
    const float* __restrict__ ref_D, const float* __restrict__ ref_mu,
    const float* __restrict__ short_e, const float* __restrict__ atomic_short,
    float* __restrict__ out) {
    __shared__ float sL[64][65];   // factor
    __shared__ float sF[64][65];   // factor * Fc
    __shared__ float s_diag[64];
    __shared__ float s_q[64];
    __shared__ float s_ash[64];
    __shared__ float s_red[16];

    const int g = blockIdx.x;
    const int tid = threadIdx.x;
    const int lane = tid & 63;
    const int wv = tid >> 6;               // 0..15; rows wv*4..wv*4+3
    const float SQRT_PI = 1.7724538509055159f;
    const float th1 = tanhf(1.0f);
    const float c1 = th1 * th1 * th1;

    // per-column (lane) type & sigma — identical in every wave
    const float4 na = *(const float4*)(node_attrs + ((size_t)((g << 6) + lane) << 2));
    const int tj = type_of(na);
    const float sgj = __expf(ref_log_sigma[tj]);
    if (tid < 64) {                         // wave 0: lane == tid
        s_diag[tid] = ref_eta[tj] + 1.0f / (sgj * SQRT_PI);
        s_ash[tid] = atomic_short[(g << 6) + tid];
    }

    // ---- phase 1: build factor / factor*Fc into LDS; E2b row sums -----------
    float e2b[4];
#pragma unroll
    for (int r = 0; r < 4; ++r) {
        const int row = (wv << 2) + r;
        const ull pk = packed[((size_t)g << 12) + (row << 6) + lane];
        const int ti = __shfl(tj, row);
        const float sgi = __shfl(sgj, row);
        const float gam = sqrtf(sgi * sgi + sgj * sgj);
        const float R = (pk > 0ull) ? __uint_as_float((unsigned)pk) : 0.5f;
        const float rinv = __frcp_rn(R);
        const float factor = erff(R * (0.70710678118654752f / gam)) * rinv;
        const float fc = fcut(R, c1);
        sL[row][lane] = factor;
        sF[row][lane] = factor * fc;
        float e = 0.0f;
        if (row != lane) {
            int t4 = ti * 4 + tj;
            float r2 = rinv * rinv;
            float r6 = r2 * r2 * r2;
            e = (ref_A[t4] * __expf(ref_B[t4] * (ref_mu[t4] - R)) -
                 ref_C[t4] * r6 - ref_D[t4] * (r6 * r2)) * fc;
        }
        e2b[r] = e;
    }
#pragma unroll
    for (int m = 1; m < 64; m <<= 1) {
#pragma unroll
        for (int r = 0; r < 4; ++r) e2b[r] += __shfl_xor(e2b[r], m);
    }
    __syncthreads();

    // ---- phase 2: fp64 dual forward substitution (wave 0 only) --------------
    if (tid < 64) {
        const int i = tid;
        double Ld = (double)(s_diag[i] + sL[i][i]);
        double inv = 1.0 / Ld;
        double au = 1.0;
        double av = (double)kappa[(g << 6) + i];
        double my_u = 0.0, my_v = 0.0;
        for (int j = 0; j < 64; ++j) {
            double ij = bcast_d(inv, j);
            double uj = bcast_d(au, j) * ij;
            double vj = bcast_d(av, j) * ij;
            if (i == j) { my_u = uj; my_v = vj; }
            if (i > j) {
                double Lij = (double)sL[i][j];
                au -= Lij * uj;
                av -= Lij * vj;
            }
        }
        double Su = wave_sum_d(my_u);
        double Sv = wave_sum_d(my_v);
        double lam = Sv / Su;  // q = -v + (Sv/Su)u  => sum(q) = 0
        s_q[i] = (float)(-my_v + lam * my_u);
    }
    __syncthreads();

    // ---- phase 3: matvec row sums + epilogue --------------------------------
    const float qj = s_q[lane];
    float pr[4], wr[4];
#pragma unroll
    for (int r = 0; r < 4; ++r) {
        const int row = (wv << 2) + r;
        pr[r] = sF[row][lane] * qj;
        wr[r] = sL[row][lane] * qj;
    }
#pragma unroll
    for (int m = 1; m < 64; m <<= 1) {
#pragma unroll
        for (int r = 0; r < 4; ++r) {
            pr[r] += __shfl_xor(pr[r], m);
            wr[r] += __shfl_xor(wr[r], m);
        }
    }
    float acc = 0.0f;
#pragma unroll
    for (int r = 0; r < 4; ++r) {
        const int row = (wv << 2) + r;
        const float q = s_q[row];
        const float sgi = __shfl(sgj, row);
        if (lane == 0) {
            float coef = 0.5f / (sgi * SQRT_PI);
            float aEel = q * (wr[r] + coef * q);
            float e2 = 0.5f * e2b[r];
            out[OUT_NODEE + row + (g << 6)] = aEel + e2 + s_ash[row];
            out[OUT_Q + row + (g << 6)] = q;
            size_t nfb = OUT_NF + (size_t)((g << 6) + row) * 130;
            out[nfb + 128] = q;
            out[nfb + 129] = pr[r];
            acc += aEel + e2;
        }
    }
    if (lane == 0) s_red[wv] = acc;
    __syncthreads();
    if (tid == 0) {
        float s = 0.0f;
#pragma unroll
        for (int k = 0; k < 16; ++k) s += s_red[k];
        out[OUT_ETOT + g] = s + short_e[g];
    }
}

extern "C" void kernel_launch(void* const* d_in, const int* in_sizes, int n_in,
                              void* d_out, int out_size, void* d_ws, size_t ws_size,
                              hipStream_t stream) {
    const float* node_attrs = (const float*)d_in[1];
    const int* edge_index = (const int*)d_in[2];
    const float* edge_length = (const float*)d_in[3];
    const float* kappa = (const float*)d_in[4];
    const float* node_feats = (const float*)d_in[5];
    const float* ref_eta = (const float*)d_in[6];
    const float* ref_log_sigma = (const float*)d_in[7];
    const float* ref_A = (const float*)d_in[8];
    const float* ref_B = (const float*)d_in[9];
    const float* ref_C = (const float*)d_in[10];
    const float* ref_D = (const float*)d_in[11];
    const float* ref_mu = (const float*)d_in[12];
    const float* short_energy = (const float*)d_in[13];
    const float* atomic_short = (const float*)d_in[14];

    float* out = (float*)d_out;
    ull* packed = (ull*)d_ws;                 // 2 MiB

    k_prep<<<512, 256, 0, stream>>>((ulonglong2*)packed, node_feats, out);
    k_scatter<<<EDGES / 256, 256, 0, stream>>>(edge_index, edge_length, packed);
    k_main<<<G, 1024, 0, stream>>>(packed, node_attrs, kappa, ref_eta,
                                   ref_log_sigma, ref_A, ref_B, ref_C, ref_D,
                                   ref_mu, short_energy, atomic_short, out);
}